// Round 9
// baseline (198.746 us; speedup 1.0000x reference)
//
#include <hip/hip_runtime.h>
#include <hip/hip_cooperative_groups.h>
#include <math.h>

namespace cg = cooperative_groups;

// Problem constants
#define NB 8      // batch
#define NC 256    // channels
#define NN 1024   // spatial H*W
#define NICH 64   // inter channels

// ws layout (float offsets)
#define WS_AQ    0        // [256]
#define WS_AK    256      // [256]
#define WS_CQ    512
#define WS_CK    513
#define WS_GE    514
#define WS_MOM   520      // [32][4]: Seq,Sek,Sek2,Sekq partials per (b,qchunk)
#define WS_SX    1024     // [8][256]
#define WS_XE    3072     // [8][256]
#define WS_XK    5120     // [8][256]
#define WS_T1P   7424     // [64]
#define WS_T2P   7488     // [64]
#define WS_VSU   7680     // [8][256]
#define WS_UE    9728     // [8][256]
#define WS_VEU   11776    // [8][256]
#define WS_CAQ   13824    // [8][256]
#define WS_CAK   15872    // [8][256]
#define WS_CUAK  17920    // [8][256]
#define WS_STAT  20480    // [8] stride 2560: eq,ek,Sv,Sve
#define STAT_STRIDE 2560
#define ST_EQ    0
#define ST_EK    1024
#define ST_SV    2048
#define ST_SVE   2304
#define WS_MAQ   40960    // [8][1024]
#define WS_MAK   49152    // [8][1024]
#define WS_EQP   57344    // [256][1024]
#define WS_EKP   319488   // [256][1024]
#define WS_MAQP  581632   // [256][1024]
#define WS_MAKP  843776   // [256][1024]
#define WS_SX2P  1105920  // [256]
#define WS_UUP   1106176  // [256]

__device__ __forceinline__ float dot4(const float4& a, const float4& b) {
    return a.x * b.x + a.y * b.y + a.z * b.z + a.w * b.w;
}
__device__ __forceinline__ float sum4(const float4& a) {
    return a.x + a.y + a.z + a.w;
}
__device__ __forceinline__ unsigned int bf16lo(float v) {
    unsigned int u = __float_as_uint(v);
    return (u + 0x7FFFu + ((u >> 16) & 1u)) >> 16;
}
__device__ __forceinline__ unsigned int bf16hi(float v) {
    unsigned int u = __float_as_uint(v);
    return (u + 0x7FFFu + ((u >> 16) & 1u)) & 0xFFFF0000u;
}

// LDS overlays (all alias one 142KB block; 1 block/CU -> 256 blocks co-resident)
struct SMemP5 {
    unsigned int Wlds2[256][128]; // row-pair packed bf16: [c][j] = (Wv[c][2j], Wv[c][2j+1])
    float VV[512];                // interleaved Vs/Ve
    float redM[256][8];           // matvec partials: 4 pa + 4 ra per thread
    float dred[9][4];
    float gred0[4];
    float gredT[2];
    float sge;
};
struct SMemP1 { float aql[8], akl[8]; float sxw[8][4]; };
struct SMemP2 { float4 qb[4][4][64]; };
struct SMemP3 { float wv8[8][8][4]; float accw[2][4]; };
struct SMemP4 { float sxl[NC], xel[NC]; float T1s[32], T2s[32]; };

__global__ void __launch_bounds__(256) mega(
        const float* __restrict__ x, const float* __restrict__ u,
        const float* __restrict__ Wq, const float* __restrict__ bq,
        const float* __restrict__ Wk, const float* __restrict__ bk,
        const float* __restrict__ Wc, const float* __restrict__ Wv,
        const float* __restrict__ bv, const float* __restrict__ gamma,
        float* __restrict__ ws, float* __restrict__ out) {
    cg::grid_group grid = cg::this_grid();
    __shared__ __align__(16) unsigned char smem_raw[sizeof(SMemP5)];
    const int bid = blockIdx.x;      // 256
    const int t = threadIdx.x;       // 256
    const int wid = t >> 6, lane = t & 63;

    // ================= P1: eq/ek/maq/mak partials + sx (round-8 k1) =========
    {
        SMemP1& S = *(SMemP1*)smem_raw;
        const int b = bid >> 5, g = bid & 31;
        const int c0 = g * 8;
        {
            const int c = t >> 5, i = t & 31;
            float a = Wc[i] * Wq[i * NC + c0 + c] + Wc[i + 32] * Wq[(i + 32) * NC + c0 + c];
            float k = Wc[64 + i] * Wk[i * NC + c0 + c] + Wc[96 + i] * Wk[(i + 32) * NC + c0 + c];
            for (int off = 16; off > 0; off >>= 1) {
                a += __shfl_down(a, off, 32);
                k += __shfl_down(k, off, 32);
            }
            if (i == 0) {
                S.aql[c] = a; S.akl[c] = k;
                ws[WS_AQ + c0 + c] = a;
                ws[WS_AK + c0 + c] = k;
            }
        }
        if (t < 64) {
            float p = Wc[t] * bq[t], r = Wc[64 + t] * bk[t];
            for (int off = 32; off > 0; off >>= 1) {
                p += __shfl_down(p, off, 64);
                r += __shfl_down(r, off, 64);
            }
            if (t == 0) { ws[WS_CQ] = p; ws[WS_CK] = r; }
        }
        __syncthreads();
        const float4* xb4 = (const float4*)(x + ((size_t)b * NC + c0) * NN);
        const float4* ub4 = (const float4*)(u + ((size_t)b * NC + c0) * NN);
        float4 eqp = {0.f, 0.f, 0.f, 0.f}, ekp = {0.f, 0.f, 0.f, 0.f};
        float4 map = {0.f, 0.f, 0.f, 0.f}, mkp = {0.f, 0.f, 0.f, 0.f};
#pragma unroll
        for (int c = 0; c < 8; ++c) {
            float4 xv = xb4[c * 256 + t];
            float4 uv = ub4[c * 256 + t];
            float a = S.aql[c], k = S.akl[c];
            eqp.x += a * xv.x; eqp.y += a * xv.y; eqp.z += a * xv.z; eqp.w += a * xv.w;
            ekp.x += k * xv.x; ekp.y += k * xv.y; ekp.z += k * xv.z; ekp.w += k * xv.w;
            map.x += a * uv.x; map.y += a * uv.y; map.z += a * uv.z; map.w += a * uv.w;
            mkp.x += k * uv.x; mkp.y += k * uv.y; mkp.z += k * uv.z; mkp.w += k * uv.w;
            float xs = sum4(xv);
            for (int off = 32; off > 0; off >>= 1) xs += __shfl_down(xs, off, 64);
            if (lane == 0) S.sxw[c][wid] = xs;
        }
        __syncthreads();
        if (t < 8) ws[WS_SX + b * NC + c0 + t] = S.sxw[t][0] + S.sxw[t][1] + S.sxw[t][2] + S.sxw[t][3];
        size_t pb = (size_t)bid * 1024;
        ((float4*)(ws + WS_EQP + pb))[t]  = eqp;
        ((float4*)(ws + WS_EKP + pb))[t]  = ekp;
        ((float4*)(ws + WS_MAQP + pb))[t] = map;
        ((float4*)(ws + WS_MAKP + pb))[t] = mkp;
    }
    grid.sync();

    // ================= P2: finalize eq/ek/maq/mak + moments (round-8 k2) ====
    if (bid < 32) {
        SMemP2& S = *(SMemP2*)smem_raw;
        const int b = bid >> 2, qc = bid & 3;
        const int quarter = t >> 6, tn = t & 63;
        const int n4 = qc * 64 + tn;
        float4 e4 = {0.f, 0.f, 0.f, 0.f}, k4 = {0.f, 0.f, 0.f, 0.f};
        float4 ma4 = {0.f, 0.f, 0.f, 0.f}, mk4 = {0.f, 0.f, 0.f, 0.f};
#pragma unroll
        for (int gg = 0; gg < 8; ++gg) {
            size_t pb = (size_t)(b * 32 + quarter * 8 + gg) * 1024;
            float4 v0 = ((const float4*)(ws + WS_EQP + pb))[n4];
            float4 v1 = ((const float4*)(ws + WS_EKP + pb))[n4];
            float4 v2 = ((const float4*)(ws + WS_MAQP + pb))[n4];
            float4 v3 = ((const float4*)(ws + WS_MAKP + pb))[n4];
            e4.x += v0.x; e4.y += v0.y; e4.z += v0.z; e4.w += v0.w;
            k4.x += v1.x; k4.y += v1.y; k4.z += v1.z; k4.w += v1.w;
            ma4.x += v2.x; ma4.y += v2.y; ma4.z += v2.z; ma4.w += v2.w;
            mk4.x += v3.x; mk4.y += v3.y; mk4.z += v3.z; mk4.w += v3.w;
        }
        S.qb[0][quarter][tn] = e4; S.qb[1][quarter][tn] = k4;
        S.qb[2][quarter][tn] = ma4; S.qb[3][quarter][tn] = mk4;
        __syncthreads();
        if (t < 64) {
            const float cq = ws[WS_CQ], ck = ws[WS_CK];
            float4 e = S.qb[0][0][t], kk = S.qb[1][0][t], ma = S.qb[2][0][t], mk = S.qb[3][0][t];
            for (int qq = 1; qq < 4; ++qq) {
                float4 a0 = S.qb[0][qq][t], a1 = S.qb[1][qq][t], a2 = S.qb[2][qq][t], a3 = S.qb[3][qq][t];
                e.x += a0.x; e.y += a0.y; e.z += a0.z; e.w += a0.w;
                kk.x += a1.x; kk.y += a1.y; kk.z += a1.z; kk.w += a1.w;
                ma.x += a2.x; ma.y += a2.y; ma.z += a2.z; ma.w += a2.w;
                mk.x += a3.x; mk.y += a3.y; mk.z += a3.z; mk.w += a3.w;
            }
            e.x += cq; e.y += cq; e.z += cq; e.w += cq;
            kk.x += ck; kk.y += ck; kk.z += ck; kk.w += ck;
            float* st = ws + WS_STAT + b * STAT_STRIDE;
            ((float4*)(st + ST_EQ))[n4] = e;
            ((float4*)(st + ST_EK))[n4] = kk;
            ((float4*)(ws + WS_MAQ + b * NN))[n4] = ma;
            ((float4*)(ws + WS_MAK + b * NN))[n4] = mk;
            float d0 = sum4(e);
            float d1 = sum4(kk);
            float d2 = dot4(kk, kk);
            float d3 = dot4(e, kk);
            for (int off = 32; off > 0; off >>= 1) {
                d0 += __shfl_down(d0, off, 64);
                d1 += __shfl_down(d1, off, 64);
                d2 += __shfl_down(d2, off, 64);
                d3 += __shfl_down(d3, off, 64);
            }
            if (t == 0) {
                ws[WS_MOM + bid * 4 + 0] = d0;
                ws[WS_MOM + bid * 4 + 1] = d1;
                ws[WS_MOM + bid * 4 + 2] = d2;
                ws[WS_MOM + bid * 4 + 3] = d3;
            }
        }
    }
    grid.sync();

    // ================= P3: fused row-dots over x and u (round-8 k3) =========
    {
        SMemP3& S = *(SMemP3*)smem_raw;
        const int b = bid >> 5, g = bid & 31;
        const int c0 = g * 8;
        const float* st = ws + WS_STAT + b * STAT_STRIDE;
        float4 e4  = ((const float4*)(st + ST_EQ))[t];
        float4 k4v = ((const float4*)(st + ST_EK))[t];
        float4 ma4 = ((const float4*)(ws + WS_MAQ + b * NN))[t];
        float4 mk4 = ((const float4*)(ws + WS_MAK + b * NN))[t];
        const float4* xb4 = (const float4*)(x + ((size_t)b * NC + c0) * NN);
        const float4* ub4 = (const float4*)(u + ((size_t)b * NC + c0) * NN);
        float x2a = 0.f, uua = 0.f;
#pragma unroll
        for (int c = 0; c < 8; ++c) {
            float4 xv = xb4[c * 256 + t];
            float4 uv = ub4[c * 256 + t];
            float d[8];
            d[0] = dot4(xv, e4);
            d[1] = dot4(xv, k4v);
            d[2] = sum4(uv);
            d[3] = dot4(uv, e4);
            d[4] = dot4(uv, k4v);
            d[5] = dot4(xv, ma4);
            d[6] = dot4(xv, mk4);
            d[7] = dot4(uv, mk4);
            x2a += dot4(xv, xv);
            uua += dot4(uv, uv);
            for (int off = 32; off > 0; off >>= 1)
                for (int m = 0; m < 8; ++m) d[m] += __shfl_down(d[m], off, 64);
            if (lane == 0) for (int m = 0; m < 8; ++m) S.wv8[c][m][wid] = d[m];
        }
        for (int off = 32; off > 0; off >>= 1) {
            x2a += __shfl_down(x2a, off, 64);
            uua += __shfl_down(uua, off, 64);
        }
        if (lane == 0) { S.accw[0][wid] = x2a; S.accw[1][wid] = uua; }
        __syncthreads();
        if (t < 8) {
            int c = t;
            float v[8];
            for (int m = 0; m < 8; ++m)
                v[m] = S.wv8[c][m][0] + S.wv8[c][m][1] + S.wv8[c][m][2] + S.wv8[c][m][3];
            ws[WS_XE   + b * NC + c0 + c] = v[0];
            ws[WS_XK   + b * NC + c0 + c] = v[1];
            ws[WS_VSU  + b * NC + c0 + c] = v[2];
            ws[WS_UE   + b * NC + c0 + c] = v[3];
            ws[WS_VEU  + b * NC + c0 + c] = v[4];
            ws[WS_CAQ  + b * NC + c0 + c] = v[5];
            ws[WS_CAK  + b * NC + c0 + c] = v[6];
            ws[WS_CUAK + b * NC + c0 + c] = v[7];
        }
        if (t == 0) {
            ws[WS_SX2P + bid] = S.accw[0][0] + S.accw[0][1] + S.accw[0][2] + S.accw[0][3];
            ws[WS_UUP + bid]  = S.accw[1][0] + S.accw[1][1] + S.accw[1][2] + S.accw[1][3];
        }
    }
    grid.sync();

    // ================= P4: Sv/Sve + T1/T2 partials (round-8 ksv) ============
    if (bid < 64) {
        SMemP4& S = *(SMemP4*)smem_raw;
        const int b = bid >> 3, oc = bid & 7;
        const int o_sub = t >> 3, ks = t & 7;
        const int o = oc * 32 + o_sub;
        S.sxl[t] = ws[WS_SX + b * NC + t];
        S.xel[t] = ws[WS_XE + b * NC + t];
        __syncthreads();
        float Seq = 0.f, Sek = 0.f, Sek2 = 0.f;
        for (int q = 0; q < 4; ++q) {
            Seq  += ws[WS_MOM + (b * 4 + q) * 4 + 0];
            Sek  += ws[WS_MOM + (b * 4 + q) * 4 + 1];
            Sek2 += ws[WS_MOM + (b * 4 + q) * 4 + 2];
        }
        const float cq = ws[WS_CQ], ck = ws[WS_CK];
        float wsx = 0.f, wxe = 0.f;
        const float4* wrow = (const float4*)(Wv + (size_t)o * NC);
#pragma unroll
        for (int i = 0; i < 8; ++i) {
            float4 w4 = wrow[i * 8 + ks];
            int k = i * 32 + ks * 4;
            wsx += w4.x * S.sxl[k] + w4.y * S.sxl[k + 1] + w4.z * S.sxl[k + 2] + w4.w * S.sxl[k + 3];
            wxe += w4.x * S.xel[k] + w4.y * S.xel[k + 1] + w4.z * S.xel[k + 2] + w4.w * S.xel[k + 3];
        }
        for (int off = 4; off > 0; off >>= 1) {
            wsx += __shfl_down(wsx, off, 8);
            wxe += __shfl_down(wxe, off, 8);
        }
        if (ks == 0) {
            float bvc = bv[o];
            float Sv  = wsx + (float)NN * bvc;
            float SvL = wsx;
            float Sve = wxe + bvc * Seq;
            float* st = ws + WS_STAT + b * STAT_STRIDE;
            st[ST_SV + o] = Sv; st[ST_SVE + o] = Sve;
            float A = 2.f * Sve - bvc * Seq - cq * Sv;
            float sx = S.sxl[o];
            float xk = ws[WS_XK + b * NC + o];
            float xkL = xk - ck * sx;
            float T1c = A * sx + Sv * xkL + SvL * xk;
            float SP  = Sek - (float)NN * ck;
            float SP2 = Sek2 - 2.f * ck * Sek + (float)NN * ck * ck;
            float SPQ = Sek2 - ck * Sek;
            float T2c = (float)NN * A * A + Sv * Sv * SP2 + SvL * SvL * Sek2
                      + 2.f * A * Sv * SP + 2.f * A * SvL * Sek + 2.f * Sv * SvL * SPQ;
            S.T1s[o_sub] = T1c; S.T2s[o_sub] = T2c;
        }
        __syncthreads();
        if (t == 0) {
            float t1 = 0.f, t2 = 0.f;
            for (int i = 0; i < 32; ++i) { t1 += S.T1s[i]; t2 += S.T2s[i]; }
            ws[WS_T1P + bid] = t1;
            ws[WS_T2P + bid] = t2;
        }
    }
    grid.sync();

    // ================= P5: 5-term vjp/trace recursion (round-8 kiter, 256t) =
    if (bid < NB) {
        SMemP5& S = *(SMemP5*)smem_raw;
        const int b = bid;
        // stage Wv -> LDS, row-pair packed bf16, fully coalesced float4 loads
        const float4* Wv4 = (const float4*)Wv;
#pragma unroll 8
        for (int r = 0; r < 64; ++r) {
            int gidx = r * 256 + t;
            float4 f = Wv4[gidx];
            int c = gidx >> 6, m = gidx & 63;
            S.Wlds2[c][2 * m]     = bf16lo(f.x) | bf16hi(f.y);
            S.Wlds2[c][2 * m + 1] = bf16lo(f.z) | bf16hi(f.w);
        }
        // gamma_eff from SX2P[256]/T1P[64]/T2P[64]
        {
            float a = ws[WS_SX2P + t];
            float b1 = 0.f, c1 = 0.f;
            if (t < 64) { b1 = ws[WS_T1P + t]; c1 = ws[WS_T2P + t]; }
            for (int off = 32; off > 0; off >>= 1) {
                a  += __shfl_down(a,  off, 64);
                b1 += __shfl_down(b1, off, 64);
                c1 += __shfl_down(c1, off, 64);
            }
            if (lane == 0) S.gred0[wid] = a;
            if (t == 0) { S.gredT[0] = b1; S.gredT[1] = c1; }
        }
        __syncthreads();
        if (t == 0) {
            float S1 = S.gred0[0] + S.gred0[1] + S.gred0[2] + S.gred0[3];
            float inv = gamma[0] * (1.f / (float)NN);
            float dd = S1 + 2.f * inv * S.gredT[0] + inv * inv * S.gredT[1];
            float lip = sqrtf(dd / S1);
            float ge = gamma[0] * ((lip > 0.9f) ? (0.9f / lip) : 1.f);
            S.sge = ge;
            if (b == 0) ws[WS_GE] = ge;
        }
        __syncthreads();
        const float s = S.sge * (1.f / (float)NN);
        const float* st = ws + WS_STAT + b * STAT_STRIDE;
        float Svl_r  = st[ST_SV + t];
        float sxl_r  = ws[WS_SX   + b * NC + t];
        float xkl_r  = ws[WS_XK   + b * NC + t];
        float caql_r = ws[WS_CAQ  + b * NC + t];
        float cakl_r = ws[WS_CAK  + b * NC + t];
        float Uel_r  = ws[WS_UE   + b * NC + t];
        float Vsul_r = ws[WS_VSU  + b * NC + t];
        float veu_r  = ws[WS_VEU  + b * NC + t];
        float cuak_r = ws[WS_CUAK + b * NC + t];
        float aql_r  = ws[WS_AQ + t];
        float akl_r  = ws[WS_AK + t];
        float bvl_r  = bv[t];
        float vsreg = Vsul_r, vereg = veu_r;
        S.VV[2 * t] = vsreg; S.VV[2 * t + 1] = vereg;
        float Seq = 0.f, Sek = 0.f, Sekq = 0.f;
        for (int qq = 0; qq < 4; ++qq) {
            Seq  += ws[WS_MOM + (b * 4 + qq) * 4 + 0];
            Sek  += ws[WS_MOM + (b * 4 + qq) * 4 + 1];
            Sekq += ws[WS_MOM + (b * 4 + qq) * 4 + 3];
        }
        float uu = 0.f;
        for (int g = 0; g < 32; ++g) uu += ws[WS_UUP + b * 32 + g];
        __syncthreads();
        // prologue dots
        {
            float d[8] = {Svl_r * cuak_r, aql_r * Vsul_r, akl_r * Vsul_r, akl_r * Uel_r,
                          Svl_r * Vsul_r, Svl_r * veu_r,  Svl_r * aql_r,  Svl_r * akl_r};
            for (int off = 32; off > 0; off >>= 1)
                for (int m = 0; m < 8; ++m) d[m] += __shfl_down(d[m], off, 64);
            if (lane == 0) for (int m = 0; m < 8; ++m) S.dred[m][wid] = d[m];
        }
        __syncthreads();
        const float g2a   = S.dred[0][0] + S.dred[0][1] + S.dred[0][2] + S.dred[0][3];
        const float aqVsu = S.dred[1][0] + S.dred[1][1] + S.dred[1][2] + S.dred[1][3];
        const float akVsu = S.dred[2][0] + S.dred[2][1] + S.dred[2][2] + S.dred[2][3];
        const float akUe  = S.dred[3][0] + S.dred[3][1] + S.dred[3][2] + S.dred[3][3];
        const float SvVsu = S.dred[4][0] + S.dred[4][1] + S.dred[4][2] + S.dred[4][3];
        const float SvVeu = S.dred[5][0] + S.dred[5][1] + S.dred[5][2] + S.dred[5][3];
        const float Svaq  = S.dred[6][0] + S.dred[6][1] + S.dred[6][2] + S.dred[6][3];
        const float Svak  = S.dred[7][0] + S.dred[7][1] + S.dred[7][2] + S.dred[7][3];
        __syncthreads();
        const float lam = 1.f + s * Svak;
        float alpha = 1.f, beta = 0.f, gam = 0.f;
        float SxAcc = 0.f, XkAcc = 0.f, CakAcc = 0.f;
        float dot = uu, tr = 0.f;
        const float coef[5] = {1.f, -0.5f, 1.f / 3.f, -0.25f, 0.2f};
        const int q4 = t & 63, cqh = t >> 6;    // 4 cols per thread, quarter of rows
        for (int j = 0; j < 5; ++j) {
            float pa0 = 0.f, pa1 = 0.f, pa2 = 0.f, pa3 = 0.f;
            float ra0 = 0.f, ra1 = 0.f, ra2 = 0.f, ra3 = 0.f;
#pragma unroll 16
            for (int i = 0; i < 64; ++i) {
                int c = cqh * 64 + i;
                uint2 w2 = *(const uint2*)&S.Wlds2[c][2 * q4];
                float2 vv = *(const float2*)&S.VV[2 * c];
                float w0 = __uint_as_float(w2.x << 16);
                float w1 = __uint_as_float(w2.x & 0xFFFF0000u);
                float w2f = __uint_as_float(w2.y << 16);
                float w3 = __uint_as_float(w2.y & 0xFFFF0000u);
                pa0 += w0 * vv.x;  ra0 += w0 * vv.y;
                pa1 += w1 * vv.x;  ra1 += w1 * vv.y;
                pa2 += w2f * vv.x; ra2 += w2f * vv.y;
                pa3 += w3 * vv.x;  ra3 += w3 * vv.y;
            }
            S.redM[t][0] = pa0; S.redM[t][1] = pa1; S.redM[t][2] = pa2; S.redM[t][3] = pa3;
            S.redM[t][4] = ra0; S.redM[t][5] = ra1; S.redM[t][6] = ra2; S.redM[t][7] = ra3;
            __syncthreads();
            // combine quarter partials: thread t = output column
            float Pv, Rv;
            {
                int q4o = t >> 2, r = t & 3;
                float pa = S.redM[q4o][r] + S.redM[64 + q4o][r]
                         + S.redM[128 + q4o][r] + S.redM[192 + q4o][r];
                float ra = S.redM[q4o][4 + r] + S.redM[64 + q4o][4 + r]
                         + S.redM[128 + q4o][4 + r] + S.redM[192 + q4o][4 + r];
                Pv = s * pa; Rv = s * ra;
            }
            {
                float d[9];
                d[0] = Svl_r * Pv;
                d[1] = Svl_r * Rv;
                d[2] = bvl_r * vsreg;
                d[3] = sxl_r * Pv;
                d[4] = xkl_r * Pv;
                d[5] = caql_r * Pv;
                d[6] = cakl_r * Pv;
                d[7] = Uel_r * Pv;
                d[8] = Vsul_r * Rv;
                for (int off = 32; off > 0; off >>= 1)
                    for (int m = 0; m < 9; ++m) d[m] += __shfl_down(d[m], off, 64);
                if (lane == 0) for (int m = 0; m < 9; ++m) S.dred[m][wid] = d[m];
            }
            __syncthreads();
            {
                float sm[9];
                for (int m = 0; m < 9; ++m)
                    sm[m] = S.dred[m][0] + S.dred[m][1] + S.dred[m][2] + S.dred[m][3];
                const float svP = sm[0], svR = sm[1], bvVs = sm[2], sxP = sm[3], xkP = sm[4],
                            caqP = sm[5], cakP = sm[6], ueP = sm[7], vsuR = sm[8];
                const float sB = s * bvVs;
                float St  = s * (alpha * SvVsu + beta * (float)NN + gam * Seq  + Svaq * SxAcc);
                float tek = s * (alpha * SvVeu + beta * Sek        + gam * Sekq + Svaq * XkAcc);
                float uta = s * (alpha * g2a   + beta * akVsu      + gam * akUe + Svaq * CakAcc);
                dot += ueP + caqP + sB * aqVsu + uta + vsuR;
                tr  += coef[j] * dot;
                float nVs = vsreg + Pv * Seq  + aql_r * (sxP + (float)NN * sB) + akl_r * St  + Rv * (float)NN;
                float nVe = vereg + Pv * Sekq + aql_r * (xkP + sB * Sek)       + akl_r * tek + Rv * Sek;
                vsreg = nVs; vereg = nVe;
                S.VV[2 * t] = nVs; S.VV[2 * t + 1] = nVe;
                SxAcc  = lam * SxAcc  + sxP;
                XkAcc  = lam * XkAcc  + xkP;
                CakAcc = lam * CakAcc + cakP;
                beta = lam * beta + Svaq * sB + svR;
                gam  = lam * gam + svP;
                alpha *= lam;
            }
            __syncthreads();
        }
        if (t == 0) out[2097152 + b] = tr;
    }
    grid.sync();

    // ================= P6: output 0, grid-stride (round-8 kout0 x8) =========
    {
        const float ge = ws[WS_GE] * (1.f / (float)NN);
#pragma unroll
        for (int it = 0; it < 8; ++it) {
            int bid2 = it * 256 + bid;
            int b = bid2 >> 8, c = bid2 & 255;
            const float* st = ws + WS_STAT + b * STAT_STRIDE;
            float sv = st[ST_SV + c], sve = st[ST_SVE + c];
            float4 ek4 = ((const float4*)(st + ST_EK))[t];
            size_t i4 = (size_t)bid2 * 256 + t;
            float4 x4 = ((const float4*)x)[i4];
            float4 o;
            o.x = 2.f * x4.x + ge * (sve + ek4.x * sv);
            o.y = 2.f * x4.y + ge * (sve + ek4.y * sv);
            o.z = 2.f * x4.z + ge * (sve + ek4.z * sv);
            o.w = 2.f * x4.w + ge * (sve + ek4.w * sv);
            ((float4*)out)[i4] = o;
        }
    }
}

extern "C" void kernel_launch(void* const* d_in, const int* in_sizes, int n_in,
                              void* d_out, int out_size, void* d_ws, size_t ws_size,
                              hipStream_t stream) {
    const float* x     = (const float*)d_in[0];
    const float* Wq    = (const float*)d_in[1];
    const float* bq    = (const float*)d_in[2];
    const float* Wk    = (const float*)d_in[3];
    const float* bk    = (const float*)d_in[4];
    const float* Wc    = (const float*)d_in[5];
    const float* Wv    = (const float*)d_in[6];
    const float* bv    = (const float*)d_in[7];
    const float* gamma = (const float*)d_in[8];
    const float* u     = (const float*)d_in[9];
    float* out = (float*)d_out;
    float* ws  = (float*)d_ws;

    void* args[] = {(void*)&x, (void*)&u, (void*)&Wq, (void*)&bq, (void*)&Wk,
                    (void*)&bk, (void*)&Wc, (void*)&Wv, (void*)&bv, (void*)&gamma,
                    (void*)&ws, (void*)&out};
    hipLaunchCooperativeKernel((void*)mega, dim3(256), dim3(256), args, 0, stream);
}

// Round 10
// 59.419 us; speedup vs baseline: 3.3448x; 3.3448x over previous
//
#include <hip/hip_runtime.h>
#include <math.h>

// Problem constants
#define NB 8      // batch
#define NC 256    // channels
#define NN 1024   // spatial H*W
#define NICH 64   // inter channels

// ws layout (float offsets)
#define WS_AQ    0        // [256]
#define WS_AK    256      // [256]
#define WS_MOM2  520      // [8][4]: Seq,Sek,Sek2,Sekq per batch
#define WS_SX    1024     // [8][256]
#define WS_XE    3072     // [8][256]
#define WS_XK    5120     // [8][256]
#define WS_T1P   7424     // [64]
#define WS_T2P   7488     // [64]
#define WS_VSU   7680     // [8][256]
#define WS_UE    9728     // [8][256]
#define WS_VEU   11776    // [8][256]
#define WS_CAQ   13824    // [8][256]
#define WS_CAK   15872    // [8][256]
#define WS_CUAK  17920    // [8][256]
#define WS_STAT  20480    // [8] stride 2560: (ek, Sv, Sve used)
#define STAT_STRIDE 2560
#define ST_EK    1024
#define ST_SV    2048
#define ST_SVE   2304
#define WS_EQP2  57344    // [16][1024] depth-2 partials (b*2+ch)
#define WS_EKP2  73728    // [16][1024]
#define WS_MAQP2 90112    // [16][1024]
#define WS_MAKP2 106496   // [16][1024]
#define WS_SX2P  123904   // [256]
#define WS_UUP   124160   // [256]

__device__ __forceinline__ float dot4(const float4& a, const float4& b) {
    return a.x * b.x + a.y * b.y + a.z * b.z + a.w * b.w;
}
__device__ __forceinline__ float sum4(const float4& a) {
    return a.x + a.y + a.z + a.w;
}
__device__ __forceinline__ unsigned int bf16lo(float v) {
    unsigned int u = __float_as_uint(v);
    return (u + 0x7FFFu + ((u >> 16) & 1u)) >> 16;
}
__device__ __forceinline__ unsigned int bf16hi(float v) {
    unsigned int u = __float_as_uint(v);
    return (u + 0x7FFFu + ((u >> 16) & 1u)) & 0xFFFF0000u;
}

// kA: depth-2 partials of eq/ek/maq/mak. 256 blocks = (b, nq in 16, ch-half).
// Each block: 128 channels x 64 columns of x and u (read exactly once).
__global__ void kA(const float* __restrict__ x, const float* __restrict__ u,
                   const float* __restrict__ Wq, const float* __restrict__ Wk,
                   const float* __restrict__ Wc, float* __restrict__ ws) {
    const int bid = blockIdx.x;
    const int b = bid >> 5, r = bid & 31;
    const int nq = r >> 1, ch = r & 1;
    const int t = threadIdx.x;   // 256
    __shared__ float aql[128], akl[128];
    __shared__ float red[4][4][64];
    // aq/ak for this 128-channel half (redundant per block; weights L2-hit)
    {
        const int c_local = t >> 1, half = t & 1;
        const int cg = ch * 128 + c_local;
        float a = 0.f, k = 0.f;
#pragma unroll 8
        for (int i = 0; i < 32; ++i) {
            int o = half * 32 + i;
            a += Wc[o] * Wq[o * NC + cg];
            k += Wc[64 + o] * Wk[o * NC + cg];
        }
        a += __shfl_xor(a, 1, 64);
        k += __shfl_xor(k, 1, 64);
        if (half == 0) {
            aql[c_local] = a; akl[c_local] = k;
            if (nq == 0) { ws[WS_AQ + cg] = a; ws[WS_AK + cg] = k; }
        }
    }
    __syncthreads();
    const int col = t & 63, grp = t >> 6;
    const int n = nq * 64 + col;
    const float* xb = x + ((size_t)b * NC + ch * 128 + grp * 32) * NN + n;
    const float* ub = u + ((size_t)b * NC + ch * 128 + grp * 32) * NN + n;
    float eqp = 0.f, ekp = 0.f, map = 0.f, mkp = 0.f;
#pragma unroll 8
    for (int i = 0; i < 32; ++i) {
        float xv = xb[(size_t)i * NN];
        float uv = ub[(size_t)i * NN];
        float a = aql[grp * 32 + i], kk = akl[grp * 32 + i];
        eqp += a * xv; ekp += kk * xv;
        map += a * uv; mkp += kk * uv;
    }
    red[grp][0][col] = eqp; red[grp][1][col] = ekp;
    red[grp][2][col] = map; red[grp][3][col] = mkp;
    __syncthreads();
    if (t < 64) {
        int idx = (b * 2 + ch) * 1024 + nq * 64 + t;
        ws[WS_EQP2  + idx] = red[0][0][t] + red[1][0][t] + red[2][0][t] + red[3][0][t];
        ws[WS_EKP2  + idx] = red[0][1][t] + red[1][1][t] + red[2][1][t] + red[3][1][t];
        ws[WS_MAQP2 + idx] = red[0][2][t] + red[1][2][t] + red[2][2][t] + red[3][2][t];
        ws[WS_MAKP2 + idx] = red[0][3][t] + red[1][3][t] + red[2][3][t] + red[3][3][t];
    }
}

// kB: finalize eq/ek/maq/mak in-register (2 partials), moments (redundant per
// block of same batch), row-dots over x,u incl. sx. 256 blocks = (b, 8-ch grp).
__global__ void kB(const float* __restrict__ x, const float* __restrict__ u,
                   const float* __restrict__ Wc, const float* __restrict__ bq,
                   const float* __restrict__ bk, float* __restrict__ ws) {
    const int bid = blockIdx.x;
    const int b = bid >> 5, g = bid & 31;
    const int c0 = g * 8;
    const int t = threadIdx.x;   // 256, = float4 group index n4
    const int wid = t >> 6, lane = t & 63;
    __shared__ float s_cq, s_ck;
    __shared__ float mred[4][4];
    __shared__ float wv9[8][9][4];
    __shared__ float accw[2][4];
    if (t < 64) {
        float p = Wc[t] * bq[t], rr = Wc[64 + t] * bk[t];
        for (int off = 32; off > 0; off >>= 1) {
            p += __shfl_down(p, off, 64);
            rr += __shfl_down(rr, off, 64);
        }
        if (t == 0) { s_cq = p; s_ck = rr; }
    }
    __syncthreads();
    const float cq = s_cq, ck = s_ck;
    float4 e4, k4, ma4, mk4;
    {
        float4 a0 = ((const float4*)(ws + WS_EQP2 + (size_t)(b * 2) * 1024))[t];
        float4 a1 = ((const float4*)(ws + WS_EQP2 + (size_t)(b * 2 + 1) * 1024))[t];
        e4.x = a0.x + a1.x + cq; e4.y = a0.y + a1.y + cq;
        e4.z = a0.z + a1.z + cq; e4.w = a0.w + a1.w + cq;
        a0 = ((const float4*)(ws + WS_EKP2 + (size_t)(b * 2) * 1024))[t];
        a1 = ((const float4*)(ws + WS_EKP2 + (size_t)(b * 2 + 1) * 1024))[t];
        k4.x = a0.x + a1.x + ck; k4.y = a0.y + a1.y + ck;
        k4.z = a0.z + a1.z + ck; k4.w = a0.w + a1.w + ck;
        a0 = ((const float4*)(ws + WS_MAQP2 + (size_t)(b * 2) * 1024))[t];
        a1 = ((const float4*)(ws + WS_MAQP2 + (size_t)(b * 2 + 1) * 1024))[t];
        ma4.x = a0.x + a1.x; ma4.y = a0.y + a1.y; ma4.z = a0.z + a1.z; ma4.w = a0.w + a1.w;
        a0 = ((const float4*)(ws + WS_MAKP2 + (size_t)(b * 2) * 1024))[t];
        a1 = ((const float4*)(ws + WS_MAKP2 + (size_t)(b * 2 + 1) * 1024))[t];
        mk4.x = a0.x + a1.x; mk4.y = a0.y + a1.y; mk4.z = a0.z + a1.z; mk4.w = a0.w + a1.w;
    }
    // moments (redundant per block; identical inputs+code -> identical value)
    {
        float d0 = sum4(e4), d1 = sum4(k4), d2 = dot4(k4, k4), d3 = dot4(e4, k4);
        for (int off = 32; off > 0; off >>= 1) {
            d0 += __shfl_down(d0, off, 64);
            d1 += __shfl_down(d1, off, 64);
            d2 += __shfl_down(d2, off, 64);
            d3 += __shfl_down(d3, off, 64);
        }
        if (lane == 0) { mred[0][wid] = d0; mred[1][wid] = d1; mred[2][wid] = d2; mred[3][wid] = d3; }
    }
    __syncthreads();
    if (t == 0)
        for (int m = 0; m < 4; ++m)
            ws[WS_MOM2 + b * 4 + m] = mred[m][0] + mred[m][1] + mred[m][2] + mred[m][3];
    if (g == 0)
        ((float4*)(ws + WS_STAT + b * STAT_STRIDE + ST_EK))[t] = k4;
    // row-dots
    const float4* xb4 = (const float4*)(x + ((size_t)b * NC + c0) * NN);
    const float4* ub4 = (const float4*)(u + ((size_t)b * NC + c0) * NN);
    float x2a = 0.f, uua = 0.f;
#pragma unroll
    for (int c = 0; c < 8; ++c) {
        float4 xv = xb4[c * 256 + t];
        float4 uv = ub4[c * 256 + t];
        float d[9];
        d[0] = dot4(xv, e4);   // xe
        d[1] = dot4(xv, k4);   // xk
        d[2] = sum4(uv);       // Vsu
        d[3] = dot4(uv, e4);   // Ue
        d[4] = dot4(uv, k4);   // Veu
        d[5] = dot4(xv, ma4);  // caq
        d[6] = dot4(xv, mk4);  // cak
        d[7] = dot4(uv, mk4);  // cuak
        d[8] = sum4(xv);       // sx
        x2a += dot4(xv, xv);
        uua += dot4(uv, uv);
        for (int off = 32; off > 0; off >>= 1)
            for (int m = 0; m < 9; ++m) d[m] += __shfl_down(d[m], off, 64);
        if (lane == 0) for (int m = 0; m < 9; ++m) wv9[c][m][wid] = d[m];
    }
    for (int off = 32; off > 0; off >>= 1) {
        x2a += __shfl_down(x2a, off, 64);
        uua += __shfl_down(uua, off, 64);
    }
    if (lane == 0) { accw[0][wid] = x2a; accw[1][wid] = uua; }
    __syncthreads();
    if (t < 8) {
        int c = t;
        float v[9];
        for (int m = 0; m < 9; ++m)
            v[m] = wv9[c][m][0] + wv9[c][m][1] + wv9[c][m][2] + wv9[c][m][3];
        ws[WS_XE   + b * NC + c0 + c] = v[0];
        ws[WS_XK   + b * NC + c0 + c] = v[1];
        ws[WS_VSU  + b * NC + c0 + c] = v[2];
        ws[WS_UE   + b * NC + c0 + c] = v[3];
        ws[WS_VEU  + b * NC + c0 + c] = v[4];
        ws[WS_CAQ  + b * NC + c0 + c] = v[5];
        ws[WS_CAK  + b * NC + c0 + c] = v[6];
        ws[WS_CUAK + b * NC + c0 + c] = v[7];
        ws[WS_SX   + b * NC + c0 + c] = v[8];
    }
    if (t == 0) {
        ws[WS_SX2P + bid] = accw[0][0] + accw[0][1] + accw[0][2] + accw[0][3];
        ws[WS_UUP + bid]  = accw[1][0] + accw[1][1] + accw[1][2] + accw[1][3];
    }
}

// ksv: Sv/Sve matvec (coalesced float4) + per-block T1/T2 partials for d2
__global__ void ksv(const float* __restrict__ Wv, const float* __restrict__ bv,
                    const float* __restrict__ Wc, const float* __restrict__ bq,
                    const float* __restrict__ bk, float* __restrict__ ws) {
    const int bid = blockIdx.x;          // 64: b*8 + oc
    const int b = bid >> 3, oc = bid & 7;
    const int t = threadIdx.x;           // 256
    const int o_sub = t >> 3, ks = t & 7;
    const int o = oc * 32 + o_sub;
    __shared__ float sxl[NC], xel[NC];
    __shared__ float T1s[32], T2s[32];
    __shared__ float s_cq, s_ck;
    if (t < 64) {
        float p = Wc[t] * bq[t], rr = Wc[64 + t] * bk[t];
        for (int off = 32; off > 0; off >>= 1) {
            p += __shfl_down(p, off, 64);
            rr += __shfl_down(rr, off, 64);
        }
        if (t == 0) { s_cq = p; s_ck = rr; }
    }
    sxl[t] = ws[WS_SX + b * NC + t];
    xel[t] = ws[WS_XE + b * NC + t];
    __syncthreads();
    const float Seq  = ws[WS_MOM2 + b * 4 + 0];
    const float Sek  = ws[WS_MOM2 + b * 4 + 1];
    const float Sek2 = ws[WS_MOM2 + b * 4 + 2];
    const float cq = s_cq, ck = s_ck;
    float wsx = 0.f, wxe = 0.f;
    const float4* wrow = (const float4*)(Wv + (size_t)o * NC);
#pragma unroll
    for (int i = 0; i < 8; ++i) {
        float4 w4 = wrow[i * 8 + ks];
        int k = i * 32 + ks * 4;
        wsx += w4.x * sxl[k] + w4.y * sxl[k + 1] + w4.z * sxl[k + 2] + w4.w * sxl[k + 3];
        wxe += w4.x * xel[k] + w4.y * xel[k + 1] + w4.z * xel[k + 2] + w4.w * xel[k + 3];
    }
    for (int off = 4; off > 0; off >>= 1) {
        wsx += __shfl_down(wsx, off, 8);
        wxe += __shfl_down(wxe, off, 8);
    }
    if (ks == 0) {
        float bvc = bv[o];
        float Sv  = wsx + (float)NN * bvc;
        float SvL = wsx;
        float Sve = wxe + bvc * Seq;
        float* st = ws + WS_STAT + b * STAT_STRIDE;
        st[ST_SV + o] = Sv; st[ST_SVE + o] = Sve;
        float A = 2.f * Sve - bvc * Seq - cq * Sv;
        float sx = sxl[o];
        float xk = ws[WS_XK + b * NC + o];
        float xkL = xk - ck * sx;
        float T1c = A * sx + Sv * xkL + SvL * xk;
        float SP  = Sek - (float)NN * ck;
        float SP2 = Sek2 - 2.f * ck * Sek + (float)NN * ck * ck;
        float SPQ = Sek2 - ck * Sek;
        float T2c = (float)NN * A * A + Sv * Sv * SP2 + SvL * SvL * Sek2
                  + 2.f * A * Sv * SP + 2.f * A * SvL * Sek + 2.f * Sv * SvL * SPQ;
        T1s[o_sub] = T1c; T2s[o_sub] = T2c;
    }
    __syncthreads();
    if (t == 0) {
        float t1 = 0.f, t2 = 0.f;
        for (int i = 0; i < 32; ++i) { t1 += T1s[i]; t2 += T2s[i]; }
        ws[WS_T1P + bid] = t1;
        ws[WS_T2P + bid] = t2;
    }
}

// kfin: blocks 0..7 = kiter (round-8, 1024t); blocks 8..519 = kout0 (4 rows).
// Both compute gamma_eff from SX2P/T1P/T2P (redundant, deterministic).
struct KFSMem {
    unsigned int Wlds[128 * 256];  // 128KB packed bf16 channel pairs
    float VV[512];
    float redPR[2048];
    float dred[9][4];
    float gred0[4];
    float gredT[2];
    float sge;
};

__global__ void kfin(const float* __restrict__ x, const float* __restrict__ Wv,
                     const float* __restrict__ bv, const float* __restrict__ gamma,
                     float* __restrict__ ws, float* __restrict__ out) {
    __shared__ __align__(16) unsigned char smem_raw[sizeof(KFSMem)];
    KFSMem& S = *(KFSMem*)smem_raw;
    const int bid = blockIdx.x;      // 520
    const int t = threadIdx.x;       // 1024
    const int lane = t & 63;
    // gamma_eff (every block; same inputs+code -> identical, deterministic)
    {
        float a = 0.f, b1 = 0.f, c1 = 0.f;
        if (t < 256) a = ws[WS_SX2P + t];
        if (t < 64) { b1 = ws[WS_T1P + t]; c1 = ws[WS_T2P + t]; }
        for (int off = 32; off > 0; off >>= 1) {
            a  += __shfl_down(a,  off, 64);
            b1 += __shfl_down(b1, off, 64);
            c1 += __shfl_down(c1, off, 64);
        }
        if (t < 256 && lane == 0) S.gred0[t >> 6] = a;
        if (t == 0) { S.gredT[0] = b1; S.gredT[1] = c1; }
    }
    __syncthreads();
    if (t == 0) {
        float S1 = S.gred0[0] + S.gred0[1] + S.gred0[2] + S.gred0[3];
        float inv = gamma[0] * (1.f / (float)NN);
        float dd = S1 + 2.f * inv * S.gredT[0] + inv * inv * S.gredT[1];
        float lip = sqrtf(dd / S1);
        S.sge = gamma[0] * ((lip > 0.9f) ? (0.9f / lip) : 1.f);
    }
    __syncthreads();
    const float ge = S.sge;

    if (bid >= 8) {
        // ---------------- kout0: 4 rows of 1024 per block -------------------
        const float gn = ge * (1.f / (float)NN);
        const int r = t >> 8, tc = t & 255;
        const int bid2 = (bid - 8) * 4 + r;
        const int b = bid2 >> 8, c = bid2 & 255;
        const float* st = ws + WS_STAT + b * STAT_STRIDE;
        float sv = st[ST_SV + c], sve = st[ST_SVE + c];
        float4 ek4 = ((const float4*)(st + ST_EK))[tc];
        size_t i4 = (size_t)bid2 * 256 + tc;
        float4 x4 = ((const float4*)x)[i4];
        float4 o;
        o.x = 2.f * x4.x + gn * (sve + ek4.x * sv);
        o.y = 2.f * x4.y + gn * (sve + ek4.y * sv);
        o.z = 2.f * x4.z + gn * (sve + ek4.z * sv);
        o.w = 2.f * x4.w + gn * (sve + ek4.w * sv);
        ((float4*)out)[i4] = o;
        return;
    }

    // ---------------- kiter: 5-term vjp/trace recursion ---------------------
    const int b = bid;
    const int o = t & 255, q = t >> 8;
    const int wid4 = o >> 6;
    // stage Wv -> LDS bf16x2 (channel-pair packing, as round 8)
#pragma unroll 4
    for (int r = 0; r < 32; ++r) {
        int c = r * 8 + q * 2;
        float w0 = Wv[(size_t)c * NC + o];
        float w1 = Wv[(size_t)(c + 1) * NC + o];
        S.Wlds[(r * 4 + q) * 256 + o] = bf16lo(w0) | bf16hi(w1);
    }
    const float s = ge * (1.f / (float)NN);
    float Svl_r = 0.f, sxl_r = 0.f, xkl_r = 0.f, caql_r = 0.f, cakl_r = 0.f,
          Uel_r = 0.f, Vsul_r = 0.f, bvl_r = 0.f, aql_r = 0.f, akl_r = 0.f,
          veu_r = 0.f, cuak_r = 0.f, vsreg = 0.f, vereg = 0.f;
    if (t < 256) {
        const float* st = ws + WS_STAT + b * STAT_STRIDE;
        Svl_r  = st[ST_SV + t];
        sxl_r  = ws[WS_SX   + b * NC + t];
        xkl_r  = ws[WS_XK   + b * NC + t];
        caql_r = ws[WS_CAQ  + b * NC + t];
        cakl_r = ws[WS_CAK  + b * NC + t];
        Uel_r  = ws[WS_UE   + b * NC + t];
        Vsul_r = ws[WS_VSU  + b * NC + t];
        veu_r  = ws[WS_VEU  + b * NC + t];
        cuak_r = ws[WS_CUAK + b * NC + t];
        aql_r  = ws[WS_AQ + t];
        akl_r  = ws[WS_AK + t];
        bvl_r  = bv[t];
        vsreg = Vsul_r; vereg = veu_r;
        S.VV[2 * t] = vsreg; S.VV[2 * t + 1] = vereg;
    }
    const float Seq  = ws[WS_MOM2 + b * 4 + 0];
    const float Sek  = ws[WS_MOM2 + b * 4 + 1];
    const float Sekq = ws[WS_MOM2 + b * 4 + 3];
    float uu = 0.f;
    for (int g = 0; g < 32; ++g) uu += ws[WS_UUP + b * 32 + g];
    __syncthreads();
    // prologue dots
    if (t < 256) {
        float d[8] = {Svl_r * cuak_r, aql_r * Vsul_r, akl_r * Vsul_r, akl_r * Uel_r,
                      Svl_r * Vsul_r, Svl_r * veu_r,  Svl_r * aql_r,  Svl_r * akl_r};
        for (int off = 32; off > 0; off >>= 1)
            for (int m = 0; m < 8; ++m) d[m] += __shfl_down(d[m], off, 64);
        if (lane == 0) for (int m = 0; m < 8; ++m) S.dred[m][wid4] = d[m];
    }
    __syncthreads();
    float g2a = 0.f, aqVsu = 0.f, akVsu = 0.f, akUe = 0.f, SvVsu = 0.f, SvVeu = 0.f,
          Svaq = 0.f, Svak = 0.f;
    if (t < 256) {
        g2a   = S.dred[0][0] + S.dred[0][1] + S.dred[0][2] + S.dred[0][3];
        aqVsu = S.dred[1][0] + S.dred[1][1] + S.dred[1][2] + S.dred[1][3];
        akVsu = S.dred[2][0] + S.dred[2][1] + S.dred[2][2] + S.dred[2][3];
        akUe  = S.dred[3][0] + S.dred[3][1] + S.dred[3][2] + S.dred[3][3];
        SvVsu = S.dred[4][0] + S.dred[4][1] + S.dred[4][2] + S.dred[4][3];
        SvVeu = S.dred[5][0] + S.dred[5][1] + S.dred[5][2] + S.dred[5][3];
        Svaq  = S.dred[6][0] + S.dred[6][1] + S.dred[6][2] + S.dred[6][3];
        Svak  = S.dred[7][0] + S.dred[7][1] + S.dred[7][2] + S.dred[7][3];
    }
    __syncthreads();
    const float lam = 1.f + s * Svak;
    float alpha = 1.f, beta = 0.f, gam = 0.f;
    float SxAcc = 0.f, XkAcc = 0.f, CakAcc = 0.f;
    float dot = uu, tr = 0.f;
    const float coef[5] = {1.f, -0.5f, 1.f / 3.f, -0.25f, 0.2f};
    for (int j = 0; j < 5; ++j) {
        float pa = 0.f, ra = 0.f;
#pragma unroll
        for (int ii = 0; ii < 32; ++ii) {
            int i = q * 32 + ii;
            unsigned int w = S.Wlds[i * 256 + o];
            float4 vv = ((const float4*)S.VV)[i];
            float wlo = __uint_as_float(w << 16);
            float whi = __uint_as_float(w & 0xFFFF0000u);
            pa += wlo * vv.x + whi * vv.z;
            ra += wlo * vv.y + whi * vv.w;
        }
        S.redPR[2 * t] = pa; S.redPR[2 * t + 1] = ra;
        __syncthreads();
        if (t < 256) {
            float Pv = s * (S.redPR[2 * t] + S.redPR[2 * (t + 256)] + S.redPR[2 * (t + 512)] + S.redPR[2 * (t + 768)]);
            float Rv = s * (S.redPR[2 * t + 1] + S.redPR[2 * (t + 256) + 1] + S.redPR[2 * (t + 512) + 1] + S.redPR[2 * (t + 768) + 1]);
            float d[9];
            d[0] = Svl_r * Pv;
            d[1] = Svl_r * Rv;
            d[2] = bvl_r * vsreg;
            d[3] = sxl_r * Pv;
            d[4] = xkl_r * Pv;
            d[5] = caql_r * Pv;
            d[6] = cakl_r * Pv;
            d[7] = Uel_r * Pv;
            d[8] = Vsul_r * Rv;
            for (int off = 32; off > 0; off >>= 1)
                for (int m = 0; m < 9; ++m) d[m] += __shfl_down(d[m], off, 64);
            if (lane == 0) for (int m = 0; m < 9; ++m) S.dred[m][wid4] = d[m];
            __syncthreads();
            float sm[9];
            for (int m = 0; m < 9; ++m)
                sm[m] = S.dred[m][0] + S.dred[m][1] + S.dred[m][2] + S.dred[m][3];
            const float svP = sm[0], svR = sm[1], bvVs = sm[2], sxP = sm[3], xkP = sm[4],
                        caqP = sm[5], cakP = sm[6], ueP = sm[7], vsuR = sm[8];
            const float sB = s * bvVs;
            float St  = s * (alpha * SvVsu + beta * (float)NN + gam * Seq  + Svaq * SxAcc);
            float tek = s * (alpha * SvVeu + beta * Sek        + gam * Sekq + Svaq * XkAcc);
            float uta = s * (alpha * g2a   + beta * akVsu      + gam * akUe + Svaq * CakAcc);
            dot += ueP + caqP + sB * aqVsu + uta + vsuR;
            tr  += coef[j] * dot;
            float nVs = vsreg + Pv * Seq  + aql_r * (sxP + (float)NN * sB) + akl_r * St  + Rv * (float)NN;
            float nVe = vereg + Pv * Sekq + aql_r * (xkP + sB * Sek)       + akl_r * tek + Rv * Sek;
            vsreg = nVs; vereg = nVe;
            S.VV[2 * t] = nVs; S.VV[2 * t + 1] = nVe;
            SxAcc  = lam * SxAcc  + sxP;
            XkAcc  = lam * XkAcc  + xkP;
            CakAcc = lam * CakAcc + cakP;
            beta = lam * beta + Svaq * sB + svR;
            gam  = lam * gam + svP;
            alpha *= lam;
        } else {
            __syncthreads();
        }
        __syncthreads();
    }
    if (t == 0) out[2097152 + b] = tr;
}

extern "C" void kernel_launch(void* const* d_in, const int* in_sizes, int n_in,
                              void* d_out, int out_size, void* d_ws, size_t ws_size,
                              hipStream_t stream) {
    const float* x     = (const float*)d_in[0];
    const float* Wq    = (const float*)d_in[1];
    const float* bq    = (const float*)d_in[2];
    const float* Wk    = (const float*)d_in[3];
    const float* bk    = (const float*)d_in[4];
    const float* Wc    = (const float*)d_in[5];
    const float* Wv    = (const float*)d_in[6];
    const float* bv    = (const float*)d_in[7];
    const float* gamma = (const float*)d_in[8];
    const float* u     = (const float*)d_in[9];
    float* out = (float*)d_out;
    float* ws  = (float*)d_ws;

    kA  <<<dim3(256), dim3(256),  0, stream>>>(x, u, Wq, Wk, Wc, ws);
    kB  <<<dim3(256), dim3(256),  0, stream>>>(x, u, Wc, bq, bk, ws);
    ksv <<<dim3(64),  dim3(256),  0, stream>>>(Wv, bv, Wc, bq, bk, ws);
    kfin<<<dim3(520), dim3(1024), 0, stream>>>(x, Wv, bv, gamma, ws, out);
}